// Round 1
// baseline (971.892 us; speedup 1.0000x reference)
//
#include <hip/hip_runtime.h>

// Seq2Seq LSTM (enc 512 steps + dec 256 steps), H=50, B=2048, input/output dim 1.
// Layout: 1 wave (64 lanes) per batch element; lane j owns hidden unit j
// (lanes 50-63 duplicate unit 49, never write). W_hh rows for the lane's 4
// gates (i,f,g,o) live permanently in 200 VGPRs; h is exchanged through a
// tiny LDS buffer read back as broadcast float4 (conflict-free).
// __launch_bounds__(64,2) -> <=256 VGPR -> 2 waves/SIMD, 8 waves/CU.

#define HID 50
#define SEQ 512
#define TGT 256

__device__ __forceinline__ float fast_sigmoid(float x) {
    return 1.0f / (1.0f + __expf(-x));   // x=+-inf safe: -> 1 / 0
}
__device__ __forceinline__ float fast_tanh(float x) {
    // 2*sigmoid(2x)-1; saturates cleanly to +-1, no NaN at extremes
    return 2.0f / (1.0f + __expf(-2.0f * x)) - 1.0f;
}

// Load this lane's 4 gate rows of W_hh (+ Wih scalar, summed bias) into regs.
#define LOAD_W(Wih, Whh, Bih, Bhh)                                   \
    {                                                                \
        _Pragma("unroll")                                            \
        for (int k = 0; k < HID; ++k) {                              \
            w0[k] = (Whh)[(0 * HID + u) * HID + k];                  \
            w1[k] = (Whh)[(1 * HID + u) * HID + k];                  \
            w2[k] = (Whh)[(2 * HID + u) * HID + k];                  \
            w3[k] = (Whh)[(3 * HID + u) * HID + k];                  \
        }                                                            \
        wx0 = (Wih)[0 * HID + u];                                    \
        wx1 = (Wih)[1 * HID + u];                                    \
        wx2 = (Wih)[2 * HID + u];                                    \
        wx3 = (Wih)[3 * HID + u];                                    \
        bb0 = (Bih)[0 * HID + u] + (Bhh)[0 * HID + u];               \
        bb1 = (Bih)[1 * HID + u] + (Bhh)[1 * HID + u];               \
        bb2 = (Bih)[2 * HID + u] + (Bhh)[2 * HID + u];               \
        bb3 = (Bih)[3 * HID + u] + (Bhh)[3 * HID + u];               \
    }

// One LSTM cell step: gates from broadcast h (LDS) + reg-resident W.
// Defines gi,gf,gg,go,hn; updates c.
#define GATES_BODY(xval)                                             \
    float a0 = fmaf(wx0, (xval), bb0);                               \
    float a1 = fmaf(wx1, (xval), bb1);                               \
    float a2 = fmaf(wx2, (xval), bb2);                               \
    float a3 = fmaf(wx3, (xval), bb3);                               \
    _Pragma("unroll")                                                \
    for (int k4 = 0; k4 < 12; ++k4) {                                \
        float4 hv = h4[k4];                                          \
        const int kb = 4 * k4;                                       \
        a0 = fmaf(w0[kb + 0], hv.x, a0);                             \
        a1 = fmaf(w1[kb + 0], hv.x, a1);                             \
        a2 = fmaf(w2[kb + 0], hv.x, a2);                             \
        a3 = fmaf(w3[kb + 0], hv.x, a3);                             \
        a0 = fmaf(w0[kb + 1], hv.y, a0);                             \
        a1 = fmaf(w1[kb + 1], hv.y, a1);                             \
        a2 = fmaf(w2[kb + 1], hv.y, a2);                             \
        a3 = fmaf(w3[kb + 1], hv.y, a3);                             \
        a0 = fmaf(w0[kb + 2], hv.z, a0);                             \
        a1 = fmaf(w1[kb + 2], hv.z, a1);                             \
        a2 = fmaf(w2[kb + 2], hv.z, a2);                             \
        a3 = fmaf(w3[kb + 2], hv.z, a3);                             \
        a0 = fmaf(w0[kb + 3], hv.w, a0);                             \
        a1 = fmaf(w1[kb + 3], hv.w, a1);                             \
        a2 = fmaf(w2[kb + 3], hv.w, a2);                             \
        a3 = fmaf(w3[kb + 3], hv.w, a3);                             \
    }                                                                \
    {                                                                \
        float hv48 = hbuf[48];                                       \
        float hv49 = hbuf[49];                                       \
        a0 = fmaf(w0[48], hv48, a0);                                 \
        a1 = fmaf(w1[48], hv48, a1);                                 \
        a2 = fmaf(w2[48], hv48, a2);                                 \
        a3 = fmaf(w3[48], hv48, a3);                                 \
        a0 = fmaf(w0[49], hv49, a0);                                 \
        a1 = fmaf(w1[49], hv49, a1);                                 \
        a2 = fmaf(w2[49], hv49, a2);                                 \
        a3 = fmaf(w3[49], hv49, a3);                                 \
    }                                                                \
    float gi = fast_sigmoid(a0);                                     \
    float gf = fast_sigmoid(a1);                                     \
    float gg = fast_tanh(a2);                                        \
    float go = fast_sigmoid(a3);                                     \
    c = fmaf(gf, c, gi * gg);                                        \
    float hn = go * fast_tanh(c);

extern "C" __global__ void __launch_bounds__(64, 2)
seq2seq_kernel(const float* __restrict__ src,
               const float* __restrict__ eWih, const float* __restrict__ eWhh,
               const float* __restrict__ eBih, const float* __restrict__ eBhh,
               const float* __restrict__ dWih, const float* __restrict__ dWhh,
               const float* __restrict__ dBih, const float* __restrict__ dBhh,
               const float* __restrict__ fcW, const float* __restrict__ fcB,
               float* __restrict__ out) {
    const int b = blockIdx.x;
    const int j = threadIdx.x;                  // lane 0..63
    const int u = (j < HID) ? j : (HID - 1);    // clamp: lanes 50-63 mirror unit 49
    const bool active = (j < HID);

    __shared__ float hbuf[56];                  // h state (50) + pad, zero-init
    if (j < 56) hbuf[j] = 0.0f;
    __syncthreads();
    const float4* h4 = (const float4*)hbuf;

    float w0[HID], w1[HID], w2[HID], w3[HID];   // reg-resident W_hh rows
    float wx0, wx1, wx2, wx3, bb0, bb1, bb2, bb3;
    float c = 0.0f;

    // ---------------- encoder: 512 steps ----------------
    LOAD_W(eWih, eWhh, eBih, eBhh);
    const float* sb = src + (size_t)b * SEQ;
    float x = sb[0];
    for (int t = 0; t < SEQ; ++t) {
        float xn = sb[(t + 1 < SEQ) ? (t + 1) : 0];  // prefetch next x
        GATES_BODY(x)
        __syncthreads();                 // all lanes done reading old h
        if (active) hbuf[j] = hn;
        __syncthreads();                 // new h visible
        x = xn;
    }

    // ---------------- decoder: 256 steps ----------------
    LOAD_W(dWih, dWhh, dBih, dBhh);
    const float fw = active ? fcW[u] : 0.0f;
    const float fb = fcB[0];
    float* ob = out + (size_t)b * TGT;

    x = 0.0f;                            // decoder_input = zeros
    for (int t = 0; t < TGT; ++t) {
        GATES_BODY(x)
        // y = fc(h): wave-wide dot(fc_W, h_new); inactive lanes contribute 0
        float p = fw * hn;
#pragma unroll
        for (int off = 32; off > 0; off >>= 1) p += __shfl_xor(p, off, 64);
        float y = p + fb;
        if (j == 0) ob[t] = y;
        __syncthreads();
        if (active) hbuf[j] = hn;
        __syncthreads();
        x = y;                           // feed output back as next input
    }
}

extern "C" void kernel_launch(void* const* d_in, const int* in_sizes, int n_in,
                              void* d_out, int out_size, void* d_ws, size_t ws_size,
                              hipStream_t stream) {
    const float* src  = (const float*)d_in[0];
    const float* eWih = (const float*)d_in[1];
    const float* eWhh = (const float*)d_in[2];
    const float* eBih = (const float*)d_in[3];
    const float* eBhh = (const float*)d_in[4];
    const float* dWih = (const float*)d_in[5];
    const float* dWhh = (const float*)d_in[6];
    const float* dBih = (const float*)d_in[7];
    const float* dBhh = (const float*)d_in[8];
    const float* fcW  = (const float*)d_in[9];
    const float* fcB  = (const float*)d_in[10];
    float* out = (float*)d_out;

    const int B = in_sizes[0] / SEQ;     // 2048
    seq2seq_kernel<<<B, 64, 0, stream>>>(src, eWih, eWhh, eBih, eBhh,
                                         dWih, dWhh, dBih, dBhh, fcW, fcB, out);
}